// Round 4
// baseline (94.759 us; speedup 1.0000x reference)
//
#include <hip/hip_runtime.h>
#include <math.h>

#define B   8
#define NL  256
#define NP  16384
#define DL  10
#define DP  4

#define DELTA  0.01f
// EPS = A_C = B_C = 1.0, L_BIND = 1.0, L_MREG = 0.1

#define NBINDBLK 256      // b(8) x pchunk(16: 1024 proteins) x lhalf(2: 128 lig atoms)
#define NMSE     8
#define NTOTBLK  (NBINDBLK + NMSE)
#define LATOMS   128      // ligand atoms per binding block
#define PBLK     4        // protein atoms per thread

typedef float v4f __attribute__((ext_vector_type(4)));

// R9: last-block-done fusion. Counter is module-scope (NOT d_ws: the workspace
// is poisoned with garbage each iteration, so it cannot hold a known-zero).
// Loaded as 0; the finishing block resets it to 0 after the final reduce, so
// every subsequent launch / graph replay starts clean.
__device__ unsigned g_done = 0;

// ---- 1-ulp HW transcendentals (guarded fallbacks) ----
static __device__ __forceinline__ float fast_sqrtf(float x) {
#if __has_builtin(__builtin_amdgcn_sqrtf)
    return __builtin_amdgcn_sqrtf(x);   // v_sqrt_f32
#else
    return sqrtf(x);
#endif
}
static __device__ __forceinline__ float fast_rcpf(float x) {
#if __has_builtin(__builtin_amdgcn_rcpf)
    return __builtin_amdgcn_rcpf(x);    // v_rcp_f32
#else
    return 1.0f / x;
#endif
}

// agent-scope helpers: partials cross XCD boundaries (per-XCD L2s are not
// coherent), so writes are release-ordered behind the done-counter and reads
// are relaxed agent-scope atomic loads after the acquire.
static __device__ __forceinline__ void store_partial(double* p, double v) {
    __hip_atomic_store(p, v, __ATOMIC_RELAXED, __HIP_MEMORY_SCOPE_AGENT);
}
static __device__ __forceinline__ double load_partial(const double* p) {
    return __hip_atomic_load(p, __ATOMIC_RELAXED, __HIP_MEMORY_SCOPE_AGENT);
}

// per-4-pair body: 13 VALU v4 ops + 4 v_sqrt + 4 v_rcp.
#define PAIR(PX, PY, PZ, EACC, VACC) do {                                    \
    v4f dx = lx - (PX), dy = ly - (PY), dz = lz - (PZ);                      \
    v4f d2 = __builtin_elementwise_fma(dx, dx,                               \
             __builtin_elementwise_fma(dy, dy, dz * dz));                    \
    v4f d;                                                                   \
    d.x = fast_sqrtf(d2.x); d.y = fast_sqrtf(d2.y);                          \
    d.z = fast_sqrtf(d2.z); d.w = fast_sqrtf(d2.w);                          \
    d += DELTA;                                                              \
    v4f inv;                                                                 \
    inv.x = fast_rcpf(d.x); inv.y = fast_rcpf(d.y);                          \
    inv.z = fast_rcpf(d.z); inv.w = fast_rcpf(d.w);                          \
    v4f inv2 = inv * inv;                                                    \
    v4f inv6 = inv2 * inv2 * inv2;                                           \
    EACC = __builtin_elementwise_fma(lw, inv, EACC);                         \
    VACC = __builtin_elementwise_fma(inv6, inv6 - 1.0f, VACC);               \
} while (0)

// ---------------------------------------------------------------------------
// Single fused kernel: binding-energy + MSE partials + last-block finalize.
//   Session model (R0-R8): the timed window = 2 x ~40 us harness poison fills
//   (256 MiB workspace each, at 84% HBM peak = their own roofline) + ~10 us
//   of ours. Fills serialize ahead of us when d_ws is consumed (R2/R7/R8)
//   and interact destructively when it is not (R6: 142 us). So partials MUST
//   stay in d_ws; the addressable budget is our ~10 us.
//   R9: finalize_kernel folded in via last-block-done reduction -> saves one
//   dispatch (~2-3 us dur + 1-2 us launch gap). Binding geometry identical
//   to R8 (P=4, lhalf=2: LDS-bus ~2.6 us, trans ~3.4 us dominant, protein
//   HBM traffic 7.3 MB). 264 blocks: 1 binding block/CU + 8 MSE blocks.
//   Deterministic fixed-order fp64 reductions throughout (no fp-atomics;
//   R3 showed a 2k-deep same-address acq_rel burst costs +25 us — here the
//   only contended atomic is 264 x u32 fetch_add on one counter).
// ---------------------------------------------------------------------------
__global__ __launch_bounds__(256, 2) void pair_mse_kernel(
    const float* __restrict__ prot_coords,   // (B,NP,3)
    const float* __restrict__ prot_feat,     // (B,NP,DP)
    const float* __restrict__ tc2,           // (B,NL,3)
    const float* __restrict__ lig_feat,      // (B,NL,DL)
    const float* __restrict__ lig_tab,       // (DL)
    const float* __restrict__ prot_tab,      // (DP)
    const float* __restrict__ pred_noise,    // (B,NL,3)
    const float* __restrict__ tgt_coords,    // (B,NL,3)
    const float* __restrict__ scaf_coords,   // (B,NL,3)
    const float* __restrict__ mask,          // (B,NL)
    double*      __restrict__ partials,
    float*       __restrict__ out)
{
    const int tid  = threadIdx.x;
    const int blk  = blockIdx.x;
    const int lane = tid & 63, w = tid >> 6;

    __shared__ double sred[4][5];
    __shared__ int slast;

    if (blk < NBINDBLK) {
        // ---------------- binding energy ----------------
        const int lhalf  = blk & 1;
        const int pchunk = (blk >> 1) & 15;
        const int b      = blk >> 5;

        __shared__ __align__(16) float sx[LATOMS], sy[LATOMS], sz[LATOMS], sw[LATOMS];
        __shared__ float sc[LATOMS * 3];      // coord bounce (384 floats)
        __shared__ float sfeat[LATOMS * DL];  // feature bounce (1280 floats)

        const int abase = b * NL + lhalf * LATOMS;

        // fully-coalesced staging
        {
            const float* csrc = tc2 + (size_t)abase * 3;
            #pragma unroll
            for (int t = tid; t < LATOMS * 3; t += 256) sc[t] = csrc[t];
            const float* fsrc = lig_feat + (size_t)abase * DL;
            #pragma unroll
            for (int t = tid; t < LATOMS * DL; t += 256) sfeat[t] = fsrc[t];
        }

        // four protein atoms for this thread (overlaps staging)
        const int m0 = b * NP + pchunk * 1024 + tid;
        const int m1 = m0 + 256;
        const int m2 = m0 + 512;
        const int m3 = m0 + 768;
        const float* pc0 = prot_coords + (size_t)m0 * 3;
        const float* pc1 = prot_coords + (size_t)m1 * 3;
        const float* pc2 = prot_coords + (size_t)m2 * 3;
        const float* pc3 = prot_coords + (size_t)m3 * 3;
        const float px0 = pc0[0], py0 = pc0[1], pz0 = pc0[2];
        const float px1 = pc1[0], py1 = pc1[1], pz1 = pc1[2];
        const float px2 = pc2[0], py2 = pc2[1], pz2 = pc2[2];
        const float px3 = pc3[0], py3 = pc3[1], pz3 = pc3[2];
        const float4 pf0 = reinterpret_cast<const float4*>(prot_feat)[m0];
        const float4 pf1 = reinterpret_cast<const float4*>(prot_feat)[m1];
        const float4 pf2 = reinterpret_cast<const float4*>(prot_feat)[m2];
        const float4 pf3 = reinterpret_cast<const float4*>(prot_feat)[m3];
        const float pt0 = prot_tab[0], pt1 = prot_tab[1];
        const float pt2 = prot_tab[2], pt3 = prot_tab[3];
        float qb, qp0, qp1, qp2, qp3;
        qb = pf0.x; qp0 = pt0;
        if (pf0.y > qb) { qb = pf0.y; qp0 = pt1; }
        if (pf0.z > qb) { qb = pf0.z; qp0 = pt2; }
        if (pf0.w > qb) { qb = pf0.w; qp0 = pt3; }
        qb = pf1.x; qp1 = pt0;
        if (pf1.y > qb) { qb = pf1.y; qp1 = pt1; }
        if (pf1.z > qb) { qb = pf1.z; qp1 = pt2; }
        if (pf1.w > qb) { qb = pf1.w; qp1 = pt3; }
        qb = pf2.x; qp2 = pt0;
        if (pf2.y > qb) { qb = pf2.y; qp2 = pt1; }
        if (pf2.z > qb) { qb = pf2.z; qp2 = pt2; }
        if (pf2.w > qb) { qb = pf2.w; qp2 = pt3; }
        qb = pf3.x; qp3 = pt0;
        if (pf3.y > qb) { qb = pf3.y; qp3 = pt1; }
        if (pf3.z > qb) { qb = pf3.z; qp3 = pt2; }
        if (pf3.w > qb) { qb = pf3.w; qp3 = pt3; }

        __syncthreads();

        // SoA build + ligand argmax from LDS (first two waves)
        if (tid < LATOMS) {
            float best = sfeat[tid * DL];
            float q = lig_tab[0];
            #pragma unroll
            for (int j = 1; j < DL; ++j) {
                float v = sfeat[tid * DL + j];
                float t = lig_tab[j];            // uniform -> s_load
                if (v > best) { best = v; q = t; }
            }
            sx[tid] = sc[tid * 3 + 0];
            sy[tid] = sc[tid * 3 + 1];
            sz[tid] = sc[tid * 3 + 2];
            sw[tid] = q;
        }
        __syncthreads();

        v4f e0 = {0.f,0.f,0.f,0.f}, e1 = {0.f,0.f,0.f,0.f};
        v4f e2 = {0.f,0.f,0.f,0.f}, e3 = {0.f,0.f,0.f,0.f};
        v4f vA = {0.f,0.f,0.f,0.f}, vB = {0.f,0.f,0.f,0.f};
        #pragma unroll 2
        for (int j = 0; j < LATOMS; j += 4) {
            v4f lx = *(const v4f*)&sx[j];        // ds_read_b128 broadcast, feeds 16 pairs
            v4f ly = *(const v4f*)&sy[j];
            v4f lz = *(const v4f*)&sz[j];
            v4f lw = *(const v4f*)&sw[j];
            PAIR(px0, py0, pz0, e0, vA);
            PAIR(px1, py1, pz1, e1, vB);
            PAIR(px2, py2, pz2, e2, vA);
            PAIR(px3, py3, pz3, e3, vB);
        }

        double e = (double)(qp0 * ((e0.x + e0.y) + (e0.z + e0.w)))
                 + (double)(qp1 * ((e1.x + e1.y) + (e1.z + e1.w)))
                 + (double)(qp2 * ((e2.x + e2.y) + (e2.z + e2.w)))
                 + (double)(qp3 * ((e3.x + e3.y) + (e3.z + e3.w)));
        double v = (double)((vA.x + vA.y) + (vA.z + vA.w))
                 + (double)((vB.x + vB.y) + (vB.z + vB.w));
        #pragma unroll
        for (int off = 32; off > 0; off >>= 1) {
            e += __shfl_down(e, off, 64);
            v += __shfl_down(v, off, 64);
        }
        if (lane == 0) { sred[w][0] = e; sred[w][1] = v; }
        __syncthreads();
        if (tid == 0) {
            store_partial(&partials[2 * blk],
                          sred[0][0] + sred[1][0] + sred[2][0] + sred[3][0]);
            store_partial(&partials[2 * blk + 1],
                          sred[0][1] + sred[1][1] + sred[2][1] + sred[3][1]);
        }
    } else {
        // ---------------- masked MSE / mreg partials ----------------
        const int idx = blk - NBINDBLK;          // [0,8)
        const int i   = idx * 256 + tid;         // [0, B*NL)
        float mk = mask[i];
        float a0 = pred_noise[3*i+0] - tgt_coords[3*i+0];
        float a1 = pred_noise[3*i+1] - tgt_coords[3*i+1];
        float a2 = pred_noise[3*i+2] - tgt_coords[3*i+2];
        double de = (double)mk * ((double)a0*a0 + (double)a1*a1 + (double)a2*a2);
        float s0 = scaf_coords[3*i+0] - tgt_coords[3*i+0];
        float s1 = scaf_coords[3*i+1] - tgt_coords[3*i+1];
        float s2 = scaf_coords[3*i+2] - tgt_coords[3*i+2];
        double mr = (double)mk * ((double)s0*s0 + (double)s1*s1 + (double)s2*s2);
        double ms = (double)mk;
        #pragma unroll
        for (int off = 32; off > 0; off >>= 1) {
            de += __shfl_down(de, off, 64);
            mr += __shfl_down(mr, off, 64);
            ms += __shfl_down(ms, off, 64);
        }
        if (lane == 0) { sred[w][0] = de; sred[w][1] = mr; sred[w][2] = ms; }
        __syncthreads();
        if (tid == 0) {
            store_partial(&partials[2*NBINDBLK + idx*3 + 0],
                          sred[0][0]+sred[1][0]+sred[2][0]+sred[3][0]);
            store_partial(&partials[2*NBINDBLK + idx*3 + 1],
                          sred[0][1]+sred[1][1]+sred[2][1]+sred[3][1]);
            store_partial(&partials[2*NBINDBLK + idx*3 + 2],
                          sred[0][2]+sred[1][2]+sred[2][2]+sred[3][2]);
        }
    }

    // ---------------- last-block-done finalize ----------------
    // tid0 order: partial stores (relaxed agent) -> release-ordered fetch_add.
    // The acquiring (last) increment synchronizes with every block's release,
    // making all partials visible to the last block's relaxed agent loads.
    if (tid == 0) {
        unsigned t = __hip_atomic_fetch_add(&g_done, 1u, __ATOMIC_ACQ_REL,
                                            __HIP_MEMORY_SCOPE_AGENT);
        slast = (t == NTOTBLK - 1);
    }
    __syncthreads();
    if (!slast) return;

    {
        double el = 0.0, vd = 0.0;
        for (int i = tid; i < NBINDBLK; i += 256) {
            el += load_partial(&partials[2*i]);
            vd += load_partial(&partials[2*i + 1]);
        }
        double de = 0.0, mr = 0.0, ms = 0.0;
        if (tid < NMSE) {
            de = load_partial(&partials[2*NBINDBLK + tid*3 + 0]);
            mr = load_partial(&partials[2*NBINDBLK + tid*3 + 1]);
            ms = load_partial(&partials[2*NBINDBLK + tid*3 + 2]);
        }
        #pragma unroll
        for (int off = 32; off > 0; off >>= 1) {
            el += __shfl_down(el, off, 64);
            vd += __shfl_down(vd, off, 64);
            de += __shfl_down(de, off, 64);
            mr += __shfl_down(mr, off, 64);
            ms += __shfl_down(ms, off, 64);
        }
        __syncthreads();   // sred reuse: binding/MSE phase reads are done
        if (lane == 0) {
            sred[w][0]=el; sred[w][1]=vd; sred[w][2]=de; sred[w][3]=mr; sred[w][4]=ms;
        }
        __syncthreads();
        if (tid == 0) {
            el = sred[0][0]+sred[1][0]+sred[2][0]+sred[3][0];
            vd = sred[0][1]+sred[1][1]+sred[2][1]+sred[3][1];
            de = sred[0][2]+sred[1][2]+sred[2][2]+sred[3][2];
            mr = sred[0][3]+sred[1][3]+sred[2][3]+sred[3][3];
            ms = sred[0][4]+sred[1][4]+sred[2][4]+sred[3][4];
            double loss_bind = (el + vd) / (double)B;
            double loss = de / ms + loss_bind + 0.1 * (mr / ms);
            out[0] = (float)loss;
            // reset for the next launch / graph replay (stream-ordered, so no
            // concurrent kernel can observe the intermediate value)
            __hip_atomic_store(&g_done, 0u, __ATOMIC_RELAXED,
                               __HIP_MEMORY_SCOPE_AGENT);
        }
    }
}

// ---------------------------------------------------------------------------
extern "C" void kernel_launch(void* const* d_in, const int* in_sizes, int n_in,
                              void* d_out, int out_size, void* d_ws, size_t ws_size,
                              hipStream_t stream)
{
    const float* pred_noise  = (const float*)d_in[0];
    const float* tgt_coords  = (const float*)d_in[1];
    const float* scaf_coords = (const float*)d_in[2];
    const float* tc2         = (const float*)d_in[3];
    const float* lig_feat    = (const float*)d_in[4];
    const float* mask        = (const float*)d_in[5];
    const float* prot_coords = (const float*)d_in[6];
    const float* prot_feat   = (const float*)d_in[7];
    const float* lig_tab     = (const float*)d_in[8];
    const float* prot_tab    = (const float*)d_in[9];
    float* out = (float*)d_out;

    double* partials = (double*)d_ws;   // 2*256 + 24 doubles = ~4.3 KB

    pair_mse_kernel<<<NTOTBLK, 256, 0, stream>>>(
        prot_coords, prot_feat, tc2, lig_feat, lig_tab, prot_tab,
        pred_noise, tgt_coords, scaf_coords, mask, partials, out);
}

// Round 5
// 90.470 us; speedup vs baseline: 1.0474x; 1.0474x over previous
//
#include <hip/hip_runtime.h>
#include <math.h>

#define B   8
#define NL  256
#define NP  16384
#define DL  10
#define DP  4

#define DELTA  0.01f
// EPS = A_C = B_C = 1.0, L_BIND = 1.0, L_MREG = 0.1

#define NBINDBLK 256      // b(8) x pchunk(16: 1024 proteins) x lhalf(2: 128 lig atoms)
#define NMSE     8
#define LATOMS   128      // ligand atoms per binding block
#define PBLK     4        // protein atoms per thread

typedef float v4f __attribute__((ext_vector_type(4)));

// ---- 1-ulp HW transcendentals (guarded fallbacks) ----
static __device__ __forceinline__ float fast_sqrtf(float x) {
#if __has_builtin(__builtin_amdgcn_sqrtf)
    return __builtin_amdgcn_sqrtf(x);   // v_sqrt_f32
#else
    return sqrtf(x);
#endif
}
static __device__ __forceinline__ float fast_rcpf(float x) {
#if __has_builtin(__builtin_amdgcn_rcpf)
    return __builtin_amdgcn_rcpf(x);    // v_rcp_f32
#else
    return 1.0f / x;
#endif
}

// per-4-pair body: 13 VALU v4 ops + 4 v_sqrt + 4 v_rcp.
#define PAIR(PX, PY, PZ, EACC, VACC) do {                                    \
    v4f dx = lx - (PX), dy = ly - (PY), dz = lz - (PZ);                      \
    v4f d2 = __builtin_elementwise_fma(dx, dx,                               \
             __builtin_elementwise_fma(dy, dy, dz * dz));                    \
    v4f d;                                                                   \
    d.x = fast_sqrtf(d2.x); d.y = fast_sqrtf(d2.y);                          \
    d.z = fast_sqrtf(d2.z); d.w = fast_sqrtf(d2.w);                          \
    d += DELTA;                                                              \
    v4f inv;                                                                 \
    inv.x = fast_rcpf(d.x); inv.y = fast_rcpf(d.y);                          \
    inv.z = fast_rcpf(d.z); inv.w = fast_rcpf(d.w);                          \
    v4f inv2 = inv * inv;                                                    \
    v4f inv6 = inv2 * inv2 * inv2;                                           \
    EACC = __builtin_elementwise_fma(lw, inv, EACC);                         \
    VACC = __builtin_elementwise_fma(inv6, inv6 - 1.0f, VACC);               \
} while (0)

// ---------------------------------------------------------------------------
// Kernel 1: binding-energy + MSE partials.  (R10 = exact revert to R8, the
//   measured 90.2 us best.)
//   Final session model (R0-R9): the timed window = 2 x ~40 us harness poison
//   fills (256 MiB workspace each, at 83-85% HBM peak = their own roofline)
//   + ~10 us of ours. Fills serialize ahead of us when d_ws is consumed
//   (R2/R7/R8) and interact destructively when it is not (R6: 142 us), so
//   partials MUST stay in d_ws. R9 proved last-block-done fusion is net
//   NEGATIVE (+4.6 us): 264 cross-XCD acq_rel atomics + a serial finalize
//   tail inside the hot kernel cost more than the ~2 us launch gap saved.
//   Two-dispatch structure is the cheaper synchronization mechanism.
//   Binding geometry: P=4, lhalf=2 — each ds_read_b128 broadcast feeds 16
//   pairs (LDS-bus ~2.6 us), protein HBM traffic 7.3 MB, trans pipe ~3.4 us
//   dominant. 256 binding blocks = 1 block/CU, 4 waves; ILP from 6
//   independent accumulator chains covers thin occupancy.
//   blocks [0,256): binding. blk -> b(8) x pchunk(16) x lhalf(2).
//   blocks [256,264): masked MSE / mreg / mask-sum partials.
//   Deterministic fixed-order fp64 block reductions -> partials (no atomics).
// ---------------------------------------------------------------------------
__global__ __launch_bounds__(256, 2) void pair_mse_kernel(
    const float* __restrict__ prot_coords,   // (B,NP,3)
    const float* __restrict__ prot_feat,     // (B,NP,DP)
    const float* __restrict__ tc2,           // (B,NL,3)
    const float* __restrict__ lig_feat,      // (B,NL,DL)
    const float* __restrict__ lig_tab,       // (DL)
    const float* __restrict__ prot_tab,      // (DP)
    const float* __restrict__ pred_noise,    // (B,NL,3)
    const float* __restrict__ tgt_coords,    // (B,NL,3)
    const float* __restrict__ scaf_coords,   // (B,NL,3)
    const float* __restrict__ mask,          // (B,NL)
    double*      __restrict__ partials)
{
    const int tid  = threadIdx.x;
    const int blk  = blockIdx.x;
    const int lane = tid & 63, w = tid >> 6;

    __shared__ double sred[4][3];

    if (blk < NBINDBLK) {
        // ---------------- binding energy ----------------
        const int lhalf  = blk & 1;
        const int pchunk = (blk >> 1) & 15;
        const int b      = blk >> 5;

        __shared__ __align__(16) float sx[LATOMS], sy[LATOMS], sz[LATOMS], sw[LATOMS];
        __shared__ float sc[LATOMS * 3];      // coord bounce (384 floats)
        __shared__ float sfeat[LATOMS * DL];  // feature bounce (1280 floats)

        const int abase = b * NL + lhalf * LATOMS;

        // fully-coalesced staging
        {
            const float* csrc = tc2 + (size_t)abase * 3;
            #pragma unroll
            for (int t = tid; t < LATOMS * 3; t += 256) sc[t] = csrc[t];
            const float* fsrc = lig_feat + (size_t)abase * DL;
            #pragma unroll
            for (int t = tid; t < LATOMS * DL; t += 256) sfeat[t] = fsrc[t];
        }

        // four protein atoms for this thread (overlaps staging)
        const int m0 = b * NP + pchunk * 1024 + tid;
        const int m1 = m0 + 256;
        const int m2 = m0 + 512;
        const int m3 = m0 + 768;
        const float* pc0 = prot_coords + (size_t)m0 * 3;
        const float* pc1 = prot_coords + (size_t)m1 * 3;
        const float* pc2 = prot_coords + (size_t)m2 * 3;
        const float* pc3 = prot_coords + (size_t)m3 * 3;
        const float px0 = pc0[0], py0 = pc0[1], pz0 = pc0[2];
        const float px1 = pc1[0], py1 = pc1[1], pz1 = pc1[2];
        const float px2 = pc2[0], py2 = pc2[1], pz2 = pc2[2];
        const float px3 = pc3[0], py3 = pc3[1], pz3 = pc3[2];
        const float4 pf0 = reinterpret_cast<const float4*>(prot_feat)[m0];
        const float4 pf1 = reinterpret_cast<const float4*>(prot_feat)[m1];
        const float4 pf2 = reinterpret_cast<const float4*>(prot_feat)[m2];
        const float4 pf3 = reinterpret_cast<const float4*>(prot_feat)[m3];
        const float pt0 = prot_tab[0], pt1 = prot_tab[1];
        const float pt2 = prot_tab[2], pt3 = prot_tab[3];
        float qb, qp0, qp1, qp2, qp3;
        qb = pf0.x; qp0 = pt0;
        if (pf0.y > qb) { qb = pf0.y; qp0 = pt1; }
        if (pf0.z > qb) { qb = pf0.z; qp0 = pt2; }
        if (pf0.w > qb) { qb = pf0.w; qp0 = pt3; }
        qb = pf1.x; qp1 = pt0;
        if (pf1.y > qb) { qb = pf1.y; qp1 = pt1; }
        if (pf1.z > qb) { qb = pf1.z; qp1 = pt2; }
        if (pf1.w > qb) { qb = pf1.w; qp1 = pt3; }
        qb = pf2.x; qp2 = pt0;
        if (pf2.y > qb) { qb = pf2.y; qp2 = pt1; }
        if (pf2.z > qb) { qb = pf2.z; qp2 = pt2; }
        if (pf2.w > qb) { qb = pf2.w; qp2 = pt3; }
        qb = pf3.x; qp3 = pt0;
        if (pf3.y > qb) { qb = pf3.y; qp3 = pt1; }
        if (pf3.z > qb) { qb = pf3.z; qp3 = pt2; }
        if (pf3.w > qb) { qb = pf3.w; qp3 = pt3; }

        __syncthreads();

        // SoA build + ligand argmax from LDS (first two waves)
        if (tid < LATOMS) {
            float best = sfeat[tid * DL];
            float q = lig_tab[0];
            #pragma unroll
            for (int j = 1; j < DL; ++j) {
                float v = sfeat[tid * DL + j];
                float t = lig_tab[j];            // uniform -> s_load
                if (v > best) { best = v; q = t; }
            }
            sx[tid] = sc[tid * 3 + 0];
            sy[tid] = sc[tid * 3 + 1];
            sz[tid] = sc[tid * 3 + 2];
            sw[tid] = q;
        }
        __syncthreads();

        v4f e0 = {0.f,0.f,0.f,0.f}, e1 = {0.f,0.f,0.f,0.f};
        v4f e2 = {0.f,0.f,0.f,0.f}, e3 = {0.f,0.f,0.f,0.f};
        v4f vA = {0.f,0.f,0.f,0.f}, vB = {0.f,0.f,0.f,0.f};
        #pragma unroll 2
        for (int j = 0; j < LATOMS; j += 4) {
            v4f lx = *(const v4f*)&sx[j];        // ds_read_b128 broadcast, feeds 16 pairs
            v4f ly = *(const v4f*)&sy[j];
            v4f lz = *(const v4f*)&sz[j];
            v4f lw = *(const v4f*)&sw[j];
            PAIR(px0, py0, pz0, e0, vA);
            PAIR(px1, py1, pz1, e1, vB);
            PAIR(px2, py2, pz2, e2, vA);
            PAIR(px3, py3, pz3, e3, vB);
        }

        double e = (double)(qp0 * ((e0.x + e0.y) + (e0.z + e0.w)))
                 + (double)(qp1 * ((e1.x + e1.y) + (e1.z + e1.w)))
                 + (double)(qp2 * ((e2.x + e2.y) + (e2.z + e2.w)))
                 + (double)(qp3 * ((e3.x + e3.y) + (e3.z + e3.w)));
        double v = (double)((vA.x + vA.y) + (vA.z + vA.w))
                 + (double)((vB.x + vB.y) + (vB.z + vB.w));
        #pragma unroll
        for (int off = 32; off > 0; off >>= 1) {
            e += __shfl_down(e, off, 64);
            v += __shfl_down(v, off, 64);
        }
        if (lane == 0) { sred[w][0] = e; sred[w][1] = v; }
        __syncthreads();
        if (tid == 0) {
            partials[2 * blk]     = sred[0][0] + sred[1][0] + sred[2][0] + sred[3][0];
            partials[2 * blk + 1] = sred[0][1] + sred[1][1] + sred[2][1] + sred[3][1];
        }
    } else {
        // ---------------- masked MSE / mreg partials ----------------
        const int idx = blk - NBINDBLK;          // [0,8)
        const int i   = idx * 256 + tid;         // [0, B*NL)
        float mk = mask[i];
        float a0 = pred_noise[3*i+0] - tgt_coords[3*i+0];
        float a1 = pred_noise[3*i+1] - tgt_coords[3*i+1];
        float a2 = pred_noise[3*i+2] - tgt_coords[3*i+2];
        double de = (double)mk * ((double)a0*a0 + (double)a1*a1 + (double)a2*a2);
        float s0 = scaf_coords[3*i+0] - tgt_coords[3*i+0];
        float s1 = scaf_coords[3*i+1] - tgt_coords[3*i+1];
        float s2 = scaf_coords[3*i+2] - tgt_coords[3*i+2];
        double mr = (double)mk * ((double)s0*s0 + (double)s1*s1 + (double)s2*s2);
        double ms = (double)mk;
        #pragma unroll
        for (int off = 32; off > 0; off >>= 1) {
            de += __shfl_down(de, off, 64);
            mr += __shfl_down(mr, off, 64);
            ms += __shfl_down(ms, off, 64);
        }
        if (lane == 0) { sred[w][0] = de; sred[w][1] = mr; sred[w][2] = ms; }
        __syncthreads();
        if (tid == 0) {
            partials[2*NBINDBLK + idx*3 + 0] = sred[0][0]+sred[1][0]+sred[2][0]+sred[3][0];
            partials[2*NBINDBLK + idx*3 + 1] = sred[0][1]+sred[1][1]+sred[2][1]+sred[3][1];
            partials[2*NBINDBLK + idx*3 + 2] = sred[0][2]+sred[1][2]+sred[2][2]+sred[3][2];
        }
    }
}

// ---------------------------------------------------------------------------
// Kernel 2: finalize — reduce all partials, write scalar loss.
// ---------------------------------------------------------------------------
__global__ __launch_bounds__(256) void finalize_kernel(
    const double* __restrict__ partials,
    float* __restrict__ out)
{
    const int tid = threadIdx.x;
    const int lane = tid & 63, w = tid >> 6;
    double el = 0.0, vd = 0.0;
    for (int i = tid; i < NBINDBLK; i += 256) {
        el += partials[2*i];
        vd += partials[2*i + 1];
    }
    double de = 0.0, mr = 0.0, ms = 0.0;
    if (tid < NMSE) {
        de = partials[2*NBINDBLK + tid*3 + 0];
        mr = partials[2*NBINDBLK + tid*3 + 1];
        ms = partials[2*NBINDBLK + tid*3 + 2];
    }
    #pragma unroll
    for (int off = 32; off > 0; off >>= 1) {
        el += __shfl_down(el, off, 64);
        vd += __shfl_down(vd, off, 64);
        de += __shfl_down(de, off, 64);
        mr += __shfl_down(mr, off, 64);
        ms += __shfl_down(ms, off, 64);
    }
    __shared__ double s[4][5];
    if (lane == 0) { s[w][0]=el; s[w][1]=vd; s[w][2]=de; s[w][3]=mr; s[w][4]=ms; }
    __syncthreads();
    if (tid == 0) {
        el = s[0][0]+s[1][0]+s[2][0]+s[3][0];
        vd = s[0][1]+s[1][1]+s[2][1]+s[3][1];
        de = s[0][2]+s[1][2]+s[2][2]+s[3][2];
        mr = s[0][3]+s[1][3]+s[2][3]+s[3][3];
        ms = s[0][4]+s[1][4]+s[2][4]+s[3][4];
        double loss_bind = (el + vd) / (double)B;
        double loss = de / ms + loss_bind + 0.1 * (mr / ms);
        out[0] = (float)loss;
    }
}

// ---------------------------------------------------------------------------
extern "C" void kernel_launch(void* const* d_in, const int* in_sizes, int n_in,
                              void* d_out, int out_size, void* d_ws, size_t ws_size,
                              hipStream_t stream)
{
    const float* pred_noise  = (const float*)d_in[0];
    const float* tgt_coords  = (const float*)d_in[1];
    const float* scaf_coords = (const float*)d_in[2];
    const float* tc2         = (const float*)d_in[3];
    const float* lig_feat    = (const float*)d_in[4];
    const float* mask        = (const float*)d_in[5];
    const float* prot_coords = (const float*)d_in[6];
    const float* prot_feat   = (const float*)d_in[7];
    const float* lig_tab     = (const float*)d_in[8];
    const float* prot_tab    = (const float*)d_in[9];
    float* out = (float*)d_out;

    double* partials = (double*)d_ws;   // 2*256 + 24 doubles = ~4.3 KB

    pair_mse_kernel<<<NBINDBLK + NMSE, 256, 0, stream>>>(
        prot_coords, prot_feat, tc2, lig_feat, lig_tab, prot_tab,
        pred_noise, tgt_coords, scaf_coords, mask, partials);
    finalize_kernel<<<1, 256, 0, stream>>>(partials, out);
}